// Round 1
// baseline (176.066 us; speedup 1.0000x reference)
//
#include <hip/hip_runtime.h>

// ConvByMoveLayer: out[b,f,o] = sum_m sum_c x[b, mask[m,f], c] * W[m,c,o] + bias[f,o]
// B=128, F=4096, C=32, O=32, M=9.
//
// Round 6: single-pass fused gather+GEMM (pass1 eliminated, no workspace).
//   Round 5 spent a full 64MB-read + 32MB-write pass converting x to fp16 only
//   to make a 16-batch slice fit one XCD's 4MB L2. Instead: keep x fp32 and
//   shrink the slice to 4 batches (4 x 4096 x 32 x 4B = 2 MB), convert
//   fp32->fp16 in-register after the gather load (identical RNE cast => same
//   numerics as round 5). Grid = 4 phases x 8 XCD x 128 field-tiles, dispatched
//   in phase order; blk%8 = XCD (round-robin dispatch, validated in round 5).
//   Per XCD+phase all 128 blocks gather from one resident 2MB slice; the
//   in-flight block window straddles <=2 phases => <=4MB transient set, fits L2.
//   Wave tile = 8 fields x 4 batches = 32 MFMA rows (W is field-independent so
//   rows mix fields freely); K = M*C = 288 = 18 x v_mfma_f32_32x32x16_f16.
//   out stores nontemporal (don't evict the slice); x gather loads regular
//   (want L2 allocation).

#define B_ 128
#define F_ 4096
#define C_ 32
#define O_ 32
#define M_ 9
#define T_ 18          // K=16 MFMA slices (M_*C_/16)

typedef _Float16 halfx8 __attribute__((ext_vector_type(8)));
typedef float floatx4 __attribute__((ext_vector_type(4)));
typedef float floatx16 __attribute__((ext_vector_type(16)));

// grid: 4*8*128 = 4096 blocks; block = 256 threads = 4 waves.
__global__ __launch_bounds__(256, 3) void fused_conv(
    const float* __restrict__ x, const int* __restrict__ mask,
    const float* __restrict__ coeffs, const float* __restrict__ biases,
    float* __restrict__ out)
{
    __shared__ _Float16 sw[T_ * 64 * 8];   // 18 KB B-fragments

    // Build B-fragment stack from global coeffs (36 KB, L2-broadcast across blocks):
    // sw[t][lane][j] = W[m = t>>1][c = 16*(t&1) + 8*(lane>>5) + j][o = lane&31]
    const int tid = threadIdx.x;
    for (int id = tid; id < T_ * 64; id += 256) {
        const int t  = id >> 6;
        const int L  = id & 63;
        const int m  = t >> 1;
        const int cb = 16 * (t & 1) + 8 * (L >> 5);
        const int oo = L & 31;
        halfx8 w;
#pragma unroll
        for (int jj = 0; jj < 8; ++jj)
            w[jj] = (_Float16)coeffs[(m * C_ + cb + jj) * O_ + oo];
        *reinterpret_cast<halfx8*>(&sw[id * 8]) = w;
    }
    __syncthreads();

    const int blk = blockIdx.x;
    const int p   = blk >> 10;          // phase 0..3 (batch super-slice, time-ordered)
    const int xcd = blk & 7;            // XCD via round-robin block dispatch
    const int ft  = (blk >> 3) & 127;   // field tile (32 fields)
    const int b0  = (p * 8 + xcd) * 4;  // this block's 4-batch slice base
    const int f0  = ft * 32;

    const int wave = tid >> 6;
    const int lane = tid & 63;
    const int h    = lane >> 5;         // K-half selector
    const int row  = lane & 31;         // MFMA M-row = fi*4 + bp
    const int fi   = row >> 2;          // field within wave tile (0..7)
    const int bp   = row & 3;           // batch within slice (0..3)
    const int o    = lane & 31;         // C/D col = output channel

    const int fw = f0 + wave * 8;       // wave's 8-field base
    const int f  = fw + fi;             // per-lane A-row field

    // Gather indices: 8 distinct fields per wave per move.
    int sidx[M_];
#pragma unroll
    for (int m = 0; m < M_; ++m) sidx[m] = mask[m * F_ + f];

    // Per-lane base into this batch's x row space; 8h folds the K-half c-offset.
    const float* xrow = x + (size_t)(b0 + bp) * (F_ * C_) + 8 * h;

    // 36 gather loads (fp32, full 128B lines per gathered field-row; v1..v3 hit
    // L1 after v0's line fill) + in-register fp16 conversion.
    halfx8 a[T_];
#pragma unroll
    for (int m = 0; m < M_; ++m) {
        const float* rp = xrow + (size_t)sidx[m] * C_;
        const floatx4 v0 = *reinterpret_cast<const floatx4*>(rp);        // c = 8h..8h+3
        const floatx4 v1 = *reinterpret_cast<const floatx4*>(rp + 4);    // c = 8h+4..8h+7
        const floatx4 v2 = *reinterpret_cast<const floatx4*>(rp + 16);   // c = 16+8h..
        const floatx4 v3 = *reinterpret_cast<const floatx4*>(rp + 20);
        halfx8 lo, hi;
#pragma unroll
        for (int jj = 0; jj < 4; ++jj) {
            lo[jj]     = (_Float16)v0[jj];
            lo[jj + 4] = (_Float16)v1[jj];
            hi[jj]     = (_Float16)v2[jj];
            hi[jj + 4] = (_Float16)v3[jj];
        }
        a[2 * m]     = lo;
        a[2 * m + 1] = hi;
    }

    floatx16 acc;
#pragma unroll
    for (int i = 0; i < 16; ++i) acc[i] = 0.0f;
#pragma unroll
    for (int t = 0; t < T_; ++t) {
        const halfx8 bwt = *reinterpret_cast<const halfx8*>(&sw[(t * 64 + lane) * 8]);
        acc = __builtin_amdgcn_mfma_f32_32x32x16_f16(a[t], bwt, acc, 0, 0, 0);
    }

    // C/D layout (m74/m101): col = lane&31, orow = (r&3) + 8*(r>>2) + 4*h
    //   => output field offset ofi = 2*(r>>2) + h, batch obp = r&3.
    // Bias: each lane needs only fields fw + 2q + h, q=0..3 (static indexing).
    float bv[4];
#pragma unroll
    for (int q = 0; q < 4; ++q)
        bv[q] = biases[(size_t)(fw + 2 * q + h) * O_ + o];

#pragma unroll
    for (int r = 0; r < 16; ++r) {
        const int q   = r >> 2;          // compile-time
        const int obp = r & 3;           // compile-time
        const float v = acc[r] + bv[q];
        __builtin_nontemporal_store(
            v, &out[((size_t)(b0 + obp) * F_ + fw + 2 * q + h) * O_ + o]);
    }
}

extern "C" void kernel_launch(void* const* d_in, const int* in_sizes, int n_in,
                              void* d_out, int out_size, void* d_ws, size_t ws_size,
                              hipStream_t stream) {
    (void)in_sizes; (void)n_in; (void)d_ws; (void)ws_size; (void)out_size;
    fused_conv<<<4 * 8 * 128, 256, 0, stream>>>(
        (const float*)d_in[0], (const int*)d_in[1],
        (const float*)d_in[2], (const float*)d_in[3], (float*)d_out);
}

// Round 2
// 144.917 us; speedup vs baseline: 1.2149x; 1.2149x over previous
//
#include <hip/hip_runtime.h>

// ConvByMoveLayer: out[b,f,o] = sum_m sum_c x[b, mask[m,f], c] * W[m,c,o] + bias[f,o]
// B=128, F=4096, C=32, O=32, M=9.
//
// Round 7: fused kernel + coalesced gather via per-wave LDS lane-transpose.
//   Round 6 (direct per-lane fp32 gather) was TA/L1-bound: each gather instr
//   touched 32 distinct 128B lines at 32B utilization (~1152 line-txns/wave).
//   Now each wave stages its 8 fields' gathered rows row-parallel (8 lanes per
//   128B row -> 8 fully-consumed lines/instr), converts fp32->fp16 in-register
//   (same RNE cast as before -> identical numerics), ds_writes into an
//   XOR-swizzled LDS tile, and ds_read_b128s the MFMA A-fragments back.
//   Waves stage only their own fields -> LDS is a private lane-transpose
//   buffer -> no barriers after the single sw-build barrier; one 3-move
//   group buffer (24 KB) is reused across the 3 K-groups (wave-ordered DS
//   ops give WAR/RAW ordering). T14 split: issue group g+1 loads -> ds_read +
//   6 MFMA of group g -> cvt + ds_write late (latency hides under MFMA).
//   Swizzle: half_idx ^= (f_l&7)<<3 on write AND read -> uniform 8 lanes per
//   bank-quad. Grid/phase/XCD mapping and epilogue unchanged from round 6.
//   LDS 18KB(sw)+24KB(al) -> 3 blocks/CU = 12 waves/CU.

#define B_ 128
#define F_ 4096
#define C_ 32
#define O_ 32
#define M_ 9
#define T_ 18          // K=16 MFMA slices (M_*C_/16)
#define GM 3           // moves per K-group
#define NG 3           // K-groups
#define FB 32          // fields per block
#define BB 4           // batches per block

typedef _Float16 halfx4 __attribute__((ext_vector_type(4)));
typedef _Float16 halfx8 __attribute__((ext_vector_type(8)));
typedef float floatx4 __attribute__((ext_vector_type(4)));
typedef float floatx16 __attribute__((ext_vector_type(16)));

// grid: 4*8*128 = 4096 blocks; block = 256 threads = 4 waves.
__global__ __launch_bounds__(256, 3) void fused_conv(
    const float* __restrict__ x, const int* __restrict__ mask,
    const float* __restrict__ coeffs, const float* __restrict__ biases,
    float* __restrict__ out)
{
    __shared__ _Float16 sw[T_ * 64 * 8];        // 18 KB B-fragments
    __shared__ _Float16 al[GM * FB * BB * C_];  // 24 KB A staging (one K-group)

    const int tid = threadIdx.x;

    // Build B-fragment stack from global coeffs (36 KB, L2-broadcast):
    // sw[t][lane][j] = W[m = t>>1][c = 16*(t&1) + 8*(lane>>5) + j][o = lane&31]
    for (int id = tid; id < T_ * 64; id += 256) {
        const int t  = id >> 6;
        const int L  = id & 63;
        const int m  = t >> 1;
        const int cb = 16 * (t & 1) + 8 * (L >> 5);
        const int oo = L & 31;
        halfx8 w;
#pragma unroll
        for (int jj = 0; jj < 8; ++jj)
            w[jj] = (_Float16)coeffs[(m * C_ + cb + jj) * O_ + oo];
        *reinterpret_cast<halfx8*>(&sw[id * 8]) = w;
    }
    __syncthreads();   // only barrier in the kernel

    const int blk = blockIdx.x;
    const int p   = blk >> 10;          // phase 0..3 (batch super-slice)
    const int xcd = blk & 7;            // XCD via round-robin block dispatch
    const int ft  = (blk >> 3) & 127;   // field tile (32 fields)
    const int b0  = (p * 8 + xcd) * 4;  // 4-batch slice base
    const int f0  = ft * 32;

    const int wave = tid >> 6;
    const int lane = tid & 63;
    const int h    = lane >> 5;         // K-half selector (compute role)
    const int row  = lane & 31;         // MFMA M-row = fi*4 + bp
    const int fi   = row >> 2;          // field within wave tile (0..7)
    const int bp   = row & 3;           // batch within slice (0..3)
    const int o    = lane & 31;         // C/D col = output channel

    const int fw = f0 + wave * 8;       // wave's 8-field base

    // Staging roles: lane covers (field sf, c-quad sc4) of a 128B row.
    const int sf  = lane >> 3;          // staged field within wave tile (0..7)
    const int sc4 = (lane & 7) * 4;     // staged c base (floats)

    // Gather indices for this lane's staged field, all 9 moves.
    int sidx[M_];
#pragma unroll
    for (int m = 0; m < M_; ++m) sidx[m] = mask[m * F_ + fw + sf];

    const float* xbase = x + (size_t)b0 * (F_ * C_) + sc4;

    // LDS half-index formulas (write and read use the SAME swizzle):
    //   write: ((ml*FB + wave*8 + sf)*BB + q )*C_ + sc4      ^ (sf<<3)
    //   read : ((ml*FB + wave*8 + fi)*BB + bp)*C_ + k*16+h*8 ^ (fi<<3)
    const int wbase = (wave * 8 + sf) * (BB * C_) + sc4;
    const int rbase = (wave * 8 + fi) * (BB * C_) + bp * C_ + h * 8;
    const int wswz  = sf << 3;
    const int rswz  = fi << 3;

    floatx16 acc;
#pragma unroll
    for (int i = 0; i < 16; ++i) acc[i] = 0.0f;

    // ---- prologue: stage K-group 0 ----
    {
        floatx4 stg[GM * BB];
#pragma unroll
        for (int ml = 0; ml < GM; ++ml)
#pragma unroll
            for (int q = 0; q < BB; ++q)
                stg[ml * BB + q] = *reinterpret_cast<const floatx4*>(
                    xbase + (size_t)q * (F_ * C_) + (size_t)sidx[ml] * C_);
#pragma unroll
        for (int ml = 0; ml < GM; ++ml)
#pragma unroll
            for (int q = 0; q < BB; ++q) {
                halfx4 hv;
#pragma unroll
                for (int jj = 0; jj < 4; ++jj)
                    hv[jj] = (_Float16)stg[ml * BB + q][jj];
                const int hw = ((ml * FB) * (BB * C_) + wbase + q * C_) ^ wswz;
                *reinterpret_cast<halfx4*>(&al[hw]) = hv;
            }
    }

    // ---- main loop over K-groups (no barriers; wave-private LDS region) ----
#pragma unroll
    for (int g = 0; g < NG; ++g) {
        // T14 issue-early: next group's 12 coalesced row loads.
        floatx4 stg[GM * BB];
        if (g < NG - 1) {
#pragma unroll
            for (int ml = 0; ml < GM; ++ml)
#pragma unroll
                for (int q = 0; q < BB; ++q)
                    stg[ml * BB + q] = *reinterpret_cast<const floatx4*>(
                        xbase + (size_t)q * (F_ * C_) +
                        (size_t)sidx[(g + 1) * GM + ml] * C_);
        }

        // A-fragments of current group from swizzled LDS.
        halfx8 af[2 * GM];
#pragma unroll
        for (int ml = 0; ml < GM; ++ml)
#pragma unroll
            for (int k = 0; k < 2; ++k) {
                const int hr = ((ml * FB) * (BB * C_) + rbase + k * 16) ^ rswz;
                af[ml * 2 + k] = *reinterpret_cast<const halfx8*>(&al[hr]);
            }

        // 6 MFMAs (K = 3 moves x 32 c).
#pragma unroll
        for (int ml = 0; ml < GM; ++ml)
#pragma unroll
            for (int k = 0; k < 2; ++k) {
                const int t = (g * GM + ml) * 2 + k;
                const halfx8 bwt =
                    *reinterpret_cast<const halfx8*>(&sw[(t * 64 + lane) * 8]);
                acc = __builtin_amdgcn_mfma_f32_32x32x16_f16(
                    af[ml * 2 + k], bwt, acc, 0, 0, 0);
            }

        // Write-late: convert + ds_write next group (after current reads).
        if (g < NG - 1) {
#pragma unroll
            for (int ml = 0; ml < GM; ++ml)
#pragma unroll
                for (int q = 0; q < BB; ++q) {
                    halfx4 hv;
#pragma unroll
                    for (int jj = 0; jj < 4; ++jj)
                        hv[jj] = (_Float16)stg[ml * BB + q][jj];
                    const int hw =
                        ((ml * FB) * (BB * C_) + wbase + q * C_) ^ wswz;
                    *reinterpret_cast<halfx4*>(&al[hw]) = hv;
                }
        }
    }

    // C/D layout (m74/m101): col = lane&31, orow = (r&3) + 8*(r>>2) + 4*h
    //   => output field offset = 2*(r>>2) + h, batch = r&3.
    float bv[4];
#pragma unroll
    for (int q = 0; q < 4; ++q)
        bv[q] = biases[(size_t)(fw + 2 * q + h) * O_ + o];

#pragma unroll
    for (int r = 0; r < 16; ++r) {
        const int q   = r >> 2;          // compile-time
        const int obp = r & 3;           // compile-time
        const float v = acc[r] + bv[q];
        __builtin_nontemporal_store(
            v, &out[((size_t)(b0 + obp) * F_ + fw + 2 * q + h) * O_ + o]);
    }
}

extern "C" void kernel_launch(void* const* d_in, const int* in_sizes, int n_in,
                              void* d_out, int out_size, void* d_ws, size_t ws_size,
                              hipStream_t stream) {
    (void)in_sizes; (void)n_in; (void)d_ws; (void)ws_size; (void)out_size;
    fused_conv<<<4 * 8 * 128, 256, 0, stream>>>(
        (const float*)d_in[0], (const int*)d_in[1],
        (const float*)d_in[2], (const float*)d_in[3], (float*)d_out);
}

// Round 3
// 141.931 us; speedup vs baseline: 1.2405x; 1.0210x over previous
//
#include <hip/hip_runtime.h>

// ConvByMoveLayer: out[b,f,o] = sum_m sum_c x[b, mask[m,f], c] * W[m,c,o] + bias[f,o]
// B=128, F=4096, C=32, O=32, M=9.
//
// Round 8: fused kernel, deep software pipeline + corrected LDS swizzle.
//   Round 7 was latency-exposed (all pipes <15%): group loads were issued and
//   consumed within the same iteration (~190cyc slack vs ~300cyc L2 latency),
//   so the VMEM queue drained every iter. Model: the structural floor is the
//   L2->L1 line-fill rate (~18.4K lines/CU, ~26us); the fix is keeping the
//   miss queue full. Two persistent register staging sets (A/B, 2-move
//   groups, 5 groups) give every consumed load a full iteration of latency
//   slack: CVT+write(set,g) -> STAGE(set,g+2) -> ds_read+MFMA(g). The A/B
//   register reuse structurally enforces the pipeline (WAR deps).
//   LDS: wave-private 4KB transpose slots (no barriers after sw build).
//   Swizzle fix: layout [ml][q][sf][c], key (row&3)<<3 halfs. Banks verified:
//   b64 writes 4cyc (min), b128 reads 8 lanes/quad (min); round 7's key
//   aliased the row stride (2.36M conflict cycles).
//   Occupancy: 34KB LDS -> 4 blocks/CU; launch_bounds(256,4) -> 16 waves/CU.

#define B_ 128
#define F_ 4096
#define C_ 32
#define O_ 32
#define M_ 9
#define T_ 18          // K=16 MFMA slices (M_*C_/16)

typedef _Float16 halfx4 __attribute__((ext_vector_type(4)));
typedef _Float16 halfx8 __attribute__((ext_vector_type(8)));
typedef float floatx4 __attribute__((ext_vector_type(4)));
typedef float floatx16 __attribute__((ext_vector_type(16)));

// Issue gather loads for NM moves (GB = first move) into register set SET.
#define STAGE(SET, GB, NM)                                                  \
  _Pragma("unroll")                                                         \
  for (int ml = 0; ml < (NM); ++ml)                                         \
    _Pragma("unroll")                                                       \
    for (int q = 0; q < 4; ++q)                                             \
      SET[ml * 4 + q] = *reinterpret_cast<const floatx4*>(                  \
          xbase + (size_t)q * (F_ * C_) + (size_t)sidx[(GB) + ml] * C_);

// Convert SET to fp16 and write into this wave's LDS slot (swizzled).
#define CVTWR(SET, NM)                                                      \
  _Pragma("unroll")                                                         \
  for (int ml = 0; ml < (NM); ++ml)                                         \
    _Pragma("unroll")                                                       \
    for (int q = 0; q < 4; ++q) {                                           \
      halfx4 hv;                                                            \
      _Pragma("unroll")                                                     \
      for (int jj = 0; jj < 4; ++jj)                                        \
        hv[jj] = (_Float16)SET[ml * 4 + q][jj];                             \
      *reinterpret_cast<halfx4*>(                                           \
          &al[wslot + ((ml * 4 + q) * 8 + sf) * 32 + ((cq * 4) ^ wkey)]) =  \
          hv;                                                               \
    }

// Read A-fragments for NM moves from the slot and run 2 MFMAs per move.
#define RDMM(GB, NM)                                                        \
  _Pragma("unroll")                                                         \
  for (int ml = 0; ml < (NM); ++ml)                                         \
    _Pragma("unroll")                                                       \
    for (int k = 0; k < 2; ++k) {                                           \
      const halfx8 af = *reinterpret_cast<const halfx8*>(                   \
          &al[wslot + ((ml * 4 + bp) * 8 + fi) * 32 +                       \
              ((k * 16 + h * 8) ^ rkey)]);                                  \
      const int t = ((GB) + ml) * 2 + k;                                    \
      const halfx8 bwt =                                                    \
          *reinterpret_cast<const halfx8*>(&sw[(t * 64 + lane) * 8]);       \
      acc = __builtin_amdgcn_mfma_f32_32x32x16_f16(af, bwt, acc, 0, 0, 0);  \
    }

// grid: 4*8*128 = 4096 blocks; block = 256 threads = 4 waves.
__global__ __launch_bounds__(256, 4) void fused_conv(
    const float* __restrict__ x, const int* __restrict__ mask,
    const float* __restrict__ coeffs, const float* __restrict__ biases,
    float* __restrict__ out)
{
    __shared__ _Float16 sw[T_ * 64 * 8];   // 18 KB B-fragments
    __shared__ _Float16 al[4 * 2048];      // 16 KB: 4 waves x 4KB transpose slot

    const int tid = threadIdx.x;

    // Build B-fragment stack (same as rounds 5-7):
    // sw[t][lane][j] = W[m=t>>1][c = 16*(t&1) + 8*(lane>>5) + j][o = lane&31]
    for (int id = tid; id < T_ * 64; id += 256) {
        const int t  = id >> 6;
        const int L  = id & 63;
        const int m  = t >> 1;
        const int cb = 16 * (t & 1) + 8 * (L >> 5);
        const int oo = L & 31;
        halfx8 w;
#pragma unroll
        for (int jj = 0; jj < 8; ++jj)
            w[jj] = (_Float16)coeffs[(m * C_ + cb + jj) * O_ + oo];
        *reinterpret_cast<halfx8*>(&sw[id * 8]) = w;
    }
    __syncthreads();   // only barrier in the kernel (al is wave-private)

    const int blk = blockIdx.x;
    const int p   = blk >> 10;          // phase 0..3 (batch super-slice)
    const int xcd = blk & 7;            // XCD via round-robin block dispatch
    const int ft  = (blk >> 3) & 127;   // field tile (32 fields)
    const int b0  = (p * 8 + xcd) * 4;  // 4-batch slice base
    const int f0  = ft * 32;

    const int wave = tid >> 6;
    const int lane = tid & 63;
    const int h    = lane >> 5;         // K-half selector
    const int row  = lane & 31;         // MFMA M-row = fi*4 + bp
    const int fi   = row >> 2;          // field within wave tile (0..7)
    const int bp   = row & 3;           // batch within slice (0..3)
    const int o    = lane & 31;         // C/D col = output channel

    const int fw = f0 + wave * 8;       // wave's 8-field base

    // Staging roles: lane = (field sf, c-quad cq) of a 128B row.
    const int sf = lane >> 3;           // staged field within wave tile
    const int cq = lane & 7;            // staged c-quad

    const int wslot = wave * 2048;      // wave's 4KB LDS slot (in halfs)
    const int wkey  = (sf & 3) << 3;    // write swizzle key (halfs)
    const int rkey  = (fi & 3) << 3;    // read swizzle key (halfs)

    // Gather indices for this lane's staged field, all 9 moves.
    int sidx[M_];
#pragma unroll
    for (int m = 0; m < M_; ++m) sidx[m] = mask[m * F_ + fw + sf];

    const float* xbase = x + (size_t)b0 * (F_ * C_) + cq * 4;

    floatx16 acc;
#pragma unroll
    for (int i = 0; i < 16; ++i) acc[i] = 0.0f;

    // ---- deep pipeline: 5 groups {2,2,2,2,1 moves}, reg sets A/B ----
    floatx4 sA[8], sB[8];
    STAGE(sA, 0, 2);                 // G0 in flight
    STAGE(sB, 2, 2);                 // G1 in flight

    CVTWR(sA, 2);  STAGE(sA, 4, 2);  RDMM(0, 2);   // g0: consume G0, issue G2
    CVTWR(sB, 2);  STAGE(sB, 6, 2);  RDMM(2, 2);   // g1: consume G1, issue G3
    CVTWR(sA, 2);  STAGE(sA, 8, 1);  RDMM(4, 2);   // g2: consume G2, issue G4
    CVTWR(sB, 2);                    RDMM(6, 2);   // g3: consume G3
    CVTWR(sA, 1);                    RDMM(8, 1);   // g4: consume G4

    // C/D layout (m74/m101): col = lane&31, orow = (r&3) + 8*(r>>2) + 4*h
    //   => output field offset = 2*(r>>2) + h, batch = r&3.
    float bv[4];
#pragma unroll
    for (int q = 0; q < 4; ++q)
        bv[q] = biases[(size_t)(fw + 2 * q + h) * O_ + o];

#pragma unroll
    for (int r = 0; r < 16; ++r) {
        const int q   = r >> 2;          // compile-time
        const int obp = r & 3;           // compile-time
        const float v = acc[r] + bv[q];
        __builtin_nontemporal_store(
            v, &out[((size_t)(b0 + obp) * F_ + fw + 2 * q + h) * O_ + o]);
    }
}

extern "C" void kernel_launch(void* const* d_in, const int* in_sizes, int n_in,
                              void* d_out, int out_size, void* d_ws, size_t ws_size,
                              hipStream_t stream) {
    (void)in_sizes; (void)n_in; (void)d_ws; (void)ws_size; (void)out_size;
    fused_conv<<<4 * 8 * 128, 256, 0, stream>>>(
        (const float*)d_in[0], (const int*)d_in[1],
        (const float*)d_in[2], (const float*)d_in[3], (float*)d_out);
}